// Round 9
// baseline (145.838 us; speedup 1.0000x reference)
//
#include <hip/hip_runtime.h>
#include <math.h>

// Chamfer distance, N=2, D=3 fp32 — grid-pruned exact NN, brick-parallel v5.
// r8 post-mortem: blocks had avg 3 queries for 256 threads (253 idle in scan,
// VALUBusy 12%) and serial thread-0 prefix sums. v5: task-parallel scan over
// (query-pair, chunk) tasks — all 256 threads busy, 2 queries per ds_read_b128
// (8 VALU/read), per-query min via LDS atomicMin on flip-keys (order-
// independent => deterministic). Wave-parallel shfl prefix sums. Pipeline
// slimmed: no cellid/rank/sidx/flag arrays; scatter places via atomicSub(hist)
// (permutes only within-cell order => candidate SET deterministic); mk is
// slot-indexed; unsolved queries marked mk=+INF, finished exactly by
// tail_brute (full scan). Exactness: margin-to-dilated-brick bound; cell_coord
// clamp is non-expansive so domain-edge faces are exhaustive; tail exhaustive.
// Determinism: single writer per mk slot; fp min order-independent;
// fixed-order final reduction.

#define G 32
#define NC (G * G * G)
#define HLO -4.5f
#define HCELL 0.28125f
#define LDS_CAP 2048
#define QMAX 256
#define TAILG 512
#define P2A_BLOCKS 6
#define P2A_PAD 8

__device__ __forceinline__ int cell_coord(float x) {
    int i = (int)floorf((x - HLO) * (32.0f / 9.0f));
    return min(max(i, 0), G - 1);
}

// Order-preserving float->uint key (works for +/-INF).
__device__ __forceinline__ unsigned fkey(float f) {
    unsigned u = __float_as_uint(f);
    unsigned mask = (unsigned)((int)u >> 31) | 0x80000000u;
    return u ^ mask;
}
__device__ __forceinline__ float fdec(unsigned k) {
    unsigned mask = (k & 0x80000000u) ? 0x80000000u : 0xFFFFFFFFu;
    return __uint_as_float(k ^ mask);
}

// ---------------- grid build / scan / scatter ----------------

__global__ __launch_bounds__(256) void grid_build(
    const float* __restrict__ c1, const float* __restrict__ c2,
    int P1, int P2, unsigned* __restrict__ hist) {
    const int set = blockIdx.y;           // n*2 + cloud
    const int n = set >> 1, cl = set & 1;
    const int P = cl ? P2 : P1;
    const int i = blockIdx.x * 256 + threadIdx.x;
    if (i >= P) return;
    const float* p = (cl ? c2 + (size_t)n * P2 * 3 : c1 + (size_t)n * P1 * 3) + (size_t)i * 3;
    const int ix = cell_coord(p[0]), iy = cell_coord(p[1]), iz = cell_coord(p[2]);
    const unsigned c = ((unsigned)iz * G + iy) * G + ix;
    atomicAdd(&hist[(size_t)set * NC + c], 1u);
}

__global__ __launch_bounds__(1024) void grid_scan(
    const unsigned* __restrict__ hist, unsigned* __restrict__ starts) {
    const int set = blockIdx.x;
    const unsigned* h = hist + (size_t)set * NC;
    unsigned* st = starts + (size_t)set * (NC + 1);
    const int t = threadIdx.x;
    const int CH = NC / 1024;             // 32
    unsigned s = 0;
    for (int k = 0; k < CH; ++k) s += h[t * CH + k];
    __shared__ unsigned sd[1024];
    sd[t] = s;
    __syncthreads();
    for (int off = 1; off < 1024; off <<= 1) {
        unsigned v = (t >= off) ? sd[t - off] : 0u;
        __syncthreads();
        sd[t] += v;
        __syncthreads();
    }
    unsigned run = (t == 0) ? 0u : sd[t - 1];
    for (int k = 0; k < CH; ++k) {
        st[t * CH + k] = run;
        run += h[t * CH + k];
    }
    if (t == 1023) st[NC] = run;          // sentinel = total
}

__global__ __launch_bounds__(256) void grid_scatter(
    const float* __restrict__ c1, const float* __restrict__ c2,
    int P1, int P2, const unsigned* __restrict__ starts,
    unsigned* __restrict__ hist, float4* __restrict__ sorted) {
    const int set = blockIdx.y;
    const int n = set >> 1, cl = set & 1;
    const int P = cl ? P2 : P1;
    const int i = blockIdx.x * 256 + threadIdx.x;
    if (i >= P) return;
    const float* p = (cl ? c2 + (size_t)n * P2 * 3 : c1 + (size_t)n * P1 * 3) + (size_t)i * 3;
    const float x = p[0], y = p[1], z = p[2];
    const int ix = cell_coord(x), iy = cell_coord(y), iz = cell_coord(z);
    const unsigned c = ((unsigned)iz * G + iy) * G + ix;
    const int poff = n * (P1 + P2) + (cl ? P1 : 0);
    // placement: atomicSub permutes only within-cell order (set unchanged)
    const unsigned pos = starts[(size_t)set * (NC + 1) + c] +
                         atomicSub(&hist[(size_t)set * NC + c], 1u) - 1u;
    sorted[poff + pos] = make_float4(-2.f * x, -2.f * y, -2.f * z,
                                     fmaf(x, x, fmaf(y, y, z * z)));
}

// ---------------- brick-parallel query (task-parallel scan) ----------------

__global__ __launch_bounds__(256) void brick_query(
    int P1, int P2, const unsigned* __restrict__ starts,
    const float4* __restrict__ sorted, float* __restrict__ mk) {
    __shared__ float4 cand[LDS_CAP];      // 32 KB
    __shared__ float4 qpt[QMAX];          // 4 KB
    __shared__ unsigned qslot[QMAX];
    __shared__ unsigned qmin[QMAX];
    __shared__ unsigned rlo[16], roff[17];
    __shared__ unsigned qlo[4], qoffp[5];
    const int zz = blockIdx.y;            // n*2 + dir
    const int n = zz >> 1, dir = zz & 1;
    const int qs = n * 2 + dir, ts = n * 2 + (1 - dir);
    const int qoff = n * (P1 + P2) + (dir ? P1 : 0);
    const int toff = n * (P1 + P2) + (dir ? 0 : P1);
    const unsigned* qst = starts + (size_t)qs * (NC + 1);
    const unsigned* tst = starts + (size_t)ts * (NC + 1);
    const float4* T = sorted + toff;
    const float4* Qs = sorted + qoff;
    const int t = threadIdx.x;
    const int bx = blockIdx.x & 15, by = (blockIdx.x >> 4) & 15, bz = blockIdx.x >> 8;
    const int x0 = max(2 * bx - 1, 0), x1 = min(2 * bx + 2, G - 1);
    const int y0 = max(2 * by - 1, 0), y1 = min(2 * by + 2, G - 1);
    const int z0 = max(2 * bz - 1, 0), z1 = min(2 * bz + 2, G - 1);
    const int ny = y1 - y0 + 1;
    const int nrows = ny * (z1 - z0 + 1);   // <= 16

    if (t < 64) {                          // wave 0: ranges + shfl prefix sums
        unsigned rc = 0;
        if (t < nrows) {
            const int zc = z0 + t / ny, yc = y0 + t % ny;
            const int base = (zc * G + yc) * G;
            const unsigned lo = tst[base + x0];
            rlo[t] = lo;
            rc = tst[base + x1 + 1] - lo;
        }
        unsigned sc = rc;
        #pragma unroll
        for (int d = 1; d < 16; d <<= 1) {
            unsigned o = __shfl_up(sc, d, 16);
            if ((t & 15) >= d) sc += o;
        }
        if (t < 16) { if (t == 0) roff[0] = 0; roff[t + 1] = sc; }
        unsigned qc = 0;
        if (t >= 16 && t < 20) {
            const int r = t - 16;
            const int zc = 2 * bz + (r >> 1), yc = 2 * by + (r & 1);
            const int qbase = (zc * G + yc) * G + 2 * bx;
            const unsigned lo = qst[qbase];
            qlo[r] = lo;
            qc = qst[qbase + 2] - lo;
        }
        unsigned sq = qc;
        #pragma unroll
        for (int d = 1; d < 4; d <<= 1) {
            unsigned o = __shfl_up(sq, d, 4);
            if ((t & 3) >= d) sq += o;
        }
        if (t >= 16 && t < 20) { if (t == 16) qoffp[0] = 0; qoffp[t - 15] = sq; }
    }
    __syncthreads();
    const unsigned nt = roff[nrows];
    const unsigned nq = qoffp[4];
    if (nq == 0) return;
    if (nt > LDS_CAP || nq > QMAX) {       // defensive overflow -> exact tail
        for (unsigned i = t; i < nq; i += 256) {
            int r = 0;
            while (r < 3 && i >= qoffp[r + 1]) ++r;
            mk[qoff + qlo[r] + (i - qoffp[r])] = INFINITY;
        }
        return;
    }
    // fill query cache (coalesced within rows)
    for (unsigned i = t; i < nq; i += 256) {
        int r = 0;
        while (r < 3 && i >= qoffp[r + 1]) ++r;
        const unsigned slot = qlo[r] + (i - qoffp[r]);
        qslot[i] = slot;
        qpt[i] = Qs[slot];
        qmin[i] = 0xFFFFFFFFu;
    }
    // stage targets: 16 lane-groups, one row each (coalesced)
    {
        const int g = t >> 4, l16 = t & 15;
        if (g < nrows) {
            const unsigned lo = rlo[g], off = roff[g], cnt = roff[g + 1] - off;
            for (unsigned k = l16; k < cnt; k += 16) cand[off + k] = T[lo + k];
        }
    }
    __syncthreads();
    if (nt > 0) {
        // tasks = (query-pair, chunk); nchunk pow2 so nqp*nchunk in [256,512)
        const unsigned nqp = (nq + 1) >> 1;
        int lsh = 0;
        while ((nqp << lsh) < 256 && lsh < 8) ++lsh;
        const unsigned nchunk = 1u << lsh;
        const unsigned ntasks = nqp << lsh;
        for (unsigned task = t; task < ntasks; task += 256) {
            const unsigned qp = task >> lsh, c = task & (nchunk - 1);
            const unsigned q0 = qp * 2, q1 = q0 + 1;
            const float4 qa = qpt[q0];
            const float4 qb = qpt[q1 < nq ? q1 : q0];
            const float ax0 = -0.5f * qa.x, ay0 = -0.5f * qa.y, az0 = -0.5f * qa.z;
            const float ax1 = -0.5f * qb.x, ay1 = -0.5f * qb.y, az1 = -0.5f * qb.z;
            float b0 = INFINITY, b1 = INFINITY;
            for (unsigned k = c; k < nt; k += nchunk) {  // consecutive lanes ->
                const float4 b = cand[k];                // consecutive float4s
                b0 = fminf(b0, fmaf(ax0, b.x, fmaf(ay0, b.y, fmaf(az0, b.z, b.w))));
                b1 = fminf(b1, fmaf(ax1, b.x, fmaf(ay1, b.y, fmaf(az1, b.z, b.w))));
            }
            atomicMin(&qmin[q0], fkey(b0));              // order-independent
            if (q1 < nq) atomicMin(&qmin[q1], fkey(b1));
        }
    }
    __syncthreads();
    // write-back with margin-to-dilated-brick test
    for (unsigned i = t; i < nq; i += 256) {
        const float4 q = qpt[i];
        const float ax = -0.5f * q.x, ay = -0.5f * q.y, az = -0.5f * q.z, qw = q.w;
        const float best = fdec(qmin[i]);
        float mg = 1e30f;
        if (x0 > 0)     mg = fminf(mg, ax - (HLO + (float)x0 * HCELL));
        if (x1 < G - 1) mg = fminf(mg, (HLO + (float)(x1 + 1) * HCELL) - ax);
        if (y0 > 0)     mg = fminf(mg, ay - (HLO + (float)y0 * HCELL));
        if (y1 < G - 1) mg = fminf(mg, (HLO + (float)(y1 + 1) * HCELL) - ay);
        if (z0 > 0)     mg = fminf(mg, az - (HLO + (float)z0 * HCELL));
        if (z1 < G - 1) mg = fminf(mg, (HLO + (float)(z1 + 1) * HCELL) - az);
        const float d2 = qw + best;
        mk[qoff + qslot[i]] = (d2 <= mg * mg) ? d2 : INFINITY;
    }
}

// ---------------- exact tail: full scan for mk==INF slots ----------------

__global__ __launch_bounds__(256) void tail_brute(
    int P1, int P2, const float4* __restrict__ sorted, float* __restrict__ mk) {
    const int zz = blockIdx.y;
    const int n = zz >> 1, dir = zz & 1;
    const int Pq = dir ? P2 : P1, Pt = dir ? P1 : P2;
    const int qoff = n * (P1 + P2) + (dir ? P1 : 0);
    const int toff = n * (P1 + P2) + (dir ? 0 : P1);
    const float4* T = sorted + toff;
    const float4* Qs = sorted + qoff;
    const int t = threadIdx.x;
    __shared__ float red[256];
    for (int q = blockIdx.x; q < Pq; q += TAILG) {
        if (!isinf(mk[qoff + q])) continue;   // block-uniform
        const float4 qd = Qs[q];
        const float ax = -0.5f * qd.x, ay = -0.5f * qd.y, az = -0.5f * qd.z;
        float best = INFINITY;
        for (int k = t; k < Pt; k += 512) {
            float4 b = T[k];
            best = fminf(best, fmaf(ax, b.x, fmaf(ay, b.y, fmaf(az, b.z, b.w))));
            int k2 = k + 256;
            if (k2 < Pt) {
                float4 b2 = T[k2];
                best = fminf(best, fmaf(ax, b2.x, fmaf(ay, b2.y, fmaf(az, b2.z, b2.w))));
            }
        }
        red[t] = best;
        __syncthreads();
        for (int o = 128; o > 0; o >>= 1) {
            if (t < o) red[t] = fminf(red[t], red[t + o]);
            __syncthreads();
        }
        if (t == 0) mk[qoff + q] = qd.w + red[0];
        __syncthreads();
    }
}

// ---------------- fused final reduction (deterministic fixed order) ----------

__global__ __launch_bounds__(1024) void reduce_all(
    const float* __restrict__ mk, int P1, int P2, float* __restrict__ out) {
    const int t = threadIdx.x;
    const int off[4] = {0, P1, P1 + P2, P1 + P2 + P1};
    const int len[4] = {P1, P2, P1, P2};
    float acc[4];
    #pragma unroll
    for (int z = 0; z < 4; ++z) {
        float s = 0.f;
        const float* p = mk + off[z];
        for (int i = t; i < len[z]; i += 1024) s += p[i];
        acc[z] = s;
    }
    __shared__ float red[1024];
    float res[4];
    for (int z = 0; z < 4; ++z) {
        red[t] = acc[z];
        __syncthreads();
        for (int o = 512; o > 0; o >>= 1) {
            if (t < o) red[t] += red[t + o];
            __syncthreads();
        }
        res[z] = red[0];
        __syncthreads();
    }
    if (t == 0) {
        out[0] = res[0] / (float)P1 + res[1] / (float)P2;
        out[1] = res[2] / (float)P1 + res[3] / (float)P2;
    }
}

// ---------------- fallback brute-force path (r2 config) ----------------

#define BLOCK 256
#define QPT 4
#define SEG 384

__global__ __launch_bounds__(BLOCK) void chamfer_pass1(
    const float* __restrict__ c1, const float* __restrict__ c2,
    int P1, int P2, unsigned* __restrict__ mk_all) {
    const int z = blockIdx.z;
    const int n = z >> 1, dir = z & 1;
    const int Pq = dir ? P2 : P1;
    const int Pt = dir ? P1 : P2;
    const float* Q = (dir ? c2 : c1) + (size_t)n * Pq * 3;
    const float* T = (dir ? c1 : c2) + (size_t)n * Pt * 3;
    unsigned* mk = mk_all + (size_t)n * (P1 + P2) + (dir ? P1 : 0);

    __shared__ float4 tile[SEG];
    const int t0 = blockIdx.y * SEG;
    const int nt = Pt - t0;
    for (int j = threadIdx.x; j < SEG; j += BLOCK) {
        float4 v;
        if (j < nt) {
            const float* p = T + (size_t)(t0 + j) * 3;
            float x = p[0], y = p[1], w = p[2];
            v = make_float4(-2.f * x, -2.f * y, -2.f * w,
                            fmaf(x, x, fmaf(y, y, w * w)));
        } else {
            v = make_float4(0.f, 0.f, 0.f, INFINITY);
        }
        tile[j] = v;
    }
    __syncthreads();

    const int qbase = blockIdx.x * (BLOCK * QPT) + threadIdx.x;
    float ax[QPT], ay[QPT], az[QPT], sq[QPT], m[QPT];
    #pragma unroll
    for (int k = 0; k < QPT; ++k) {
        const int qi = qbase + k * BLOCK;
        ax[k] = 0.f; ay[k] = 0.f; az[k] = 0.f;
        if (qi < Pq) {
            const float* p = Q + (size_t)qi * 3;
            ax[k] = p[0]; ay[k] = p[1]; az[k] = p[2];
        }
        sq[k] = fmaf(ax[k], ax[k], fmaf(ay[k], ay[k], az[k] * az[k]));
        m[k] = INFINITY;
    }
    #pragma unroll 4
    for (int j = 0; j < SEG; j += 2) {
        float4 b0 = tile[j];
        float4 b1 = tile[j + 1];
        #pragma unroll
        for (int k = 0; k < QPT; ++k) {
            float d0 = fmaf(ax[k], b0.x, fmaf(ay[k], b0.y, fmaf(az[k], b0.z, b0.w)));
            float d1 = fmaf(ax[k], b1.x, fmaf(ay[k], b1.y, fmaf(az[k], b1.z, b1.w)));
            m[k] = fminf(fminf(m[k], d0), d1);
        }
    }
    #pragma unroll
    for (int k = 0; k < QPT; ++k) {
        const int qi = qbase + k * BLOCK;
        if (qi < Pq) atomicMin(&mk[qi], fkey(sq[k] + m[k]));
    }
}

__global__ __launch_bounds__(256) void pass2a_key(
    const unsigned* __restrict__ mk_all, int P1, int P2,
    float* __restrict__ partial) {
    const int z = blockIdx.y;
    const int b = blockIdx.x;
    const int n = z >> 1, dir = z & 1;
    const int Pq = dir ? P2 : P1;
    const unsigned* mk = mk_all + (size_t)n * (P1 + P2) + (dir ? P1 : 0);
    const int span = (Pq + P2A_BLOCKS - 1) / P2A_BLOCKS;
    const int lo = b * span;
    const int hi = min(lo + span, Pq);
    float s = 0.f;
    for (int q = lo + threadIdx.x; q < hi; q += 256) s += fdec(mk[q]);
    __shared__ float red[256];
    red[threadIdx.x] = s;
    __syncthreads();
    for (int off = 128; off > 0; off >>= 1) {
        if (threadIdx.x < off) red[threadIdx.x] += red[threadIdx.x + off];
        __syncthreads();
    }
    if (threadIdx.x == 0) partial[z * P2A_PAD + b] = red[0];
}

__global__ void pass2b(const float* __restrict__ partial,
                       int P1, int P2, float* __restrict__ out) {
    int n = threadIdx.x;
    if (n < 2) {
        float sA = 0.f, sB = 0.f;
        for (int b = 0; b < P2A_BLOCKS; ++b) {
            sA += partial[(n * 2 + 0) * P2A_PAD + b];
            sB += partial[(n * 2 + 1) * P2A_PAD + b];
        }
        out[n] = sA / (float)P1 + sB / (float)P2;
    }
}

// ---------------- launch ----------------

static inline size_t al256(size_t x) { return (x + 255) & ~(size_t)255; }

extern "C" void kernel_launch(void* const* d_in, const int* in_sizes, int n_in,
                              void* d_out, int out_size, void* d_ws, size_t ws_size,
                              hipStream_t stream) {
    const float* c1 = (const float*)d_in[0];
    const float* c2 = (const float*)d_in[1];
    const int N = 2;
    const int P1 = in_sizes[0] / (N * 3);
    const int P2 = in_sizes[1] / (N * 3);
    const int TP = N * (P1 + P2);
    const int Pmax = P1 > P2 ? P1 : P2;

    // ws layout (256-aligned)
    size_t o_hist = 0;
    size_t o_starts = al256(o_hist + (size_t)4 * NC * 4);
    size_t o_mk = al256(o_starts + (size_t)4 * (NC + 1) * 4);
    size_t o_part = al256(o_mk + (size_t)TP * 4);
    size_t o_sorted = al256(o_part + (size_t)4 * P2A_PAD * 4);
    size_t need = o_sorted + (size_t)TP * 16;

    char* ws = (char*)d_ws;
    float* partial = (float*)(ws + o_part);

    if (ws_size >= need) {
        unsigned* hist = (unsigned*)(ws + o_hist);
        unsigned* starts = (unsigned*)(ws + o_starts);
        float* mk = (float*)(ws + o_mk);
        float4* sorted = (float4*)(ws + o_sorted);

        hipMemsetAsync(hist, 0, (size_t)4 * NC * 4, stream);

        dim3 gb((Pmax + 255) / 256, 4);
        grid_build<<<gb, 256, 0, stream>>>(c1, c2, P1, P2, hist);
        grid_scan<<<4, 1024, 0, stream>>>(hist, starts);
        grid_scatter<<<gb, 256, 0, stream>>>(c1, c2, P1, P2, starts, hist, sorted);
        brick_query<<<dim3(4096, 4), 256, 0, stream>>>(P1, P2, starts, sorted, mk);
        tail_brute<<<dim3(TAILG, 4), 256, 0, stream>>>(P1, P2, sorted, mk);
        reduce_all<<<1, 1024, 0, stream>>>(mk, P1, P2, (float*)d_out);
    } else {
        // fallback: brute force (r2 config)
        unsigned* mku = (unsigned*)(ws + o_mk);
        hipMemsetAsync(mku, 0xFF, (size_t)TP * 4, stream);
        dim3 g1((Pmax + BLOCK * QPT - 1) / (BLOCK * QPT),
                (Pmax + SEG - 1) / SEG, 2 * N);
        chamfer_pass1<<<g1, BLOCK, 0, stream>>>(c1, c2, P1, P2, mku);
        dim3 g2(P2A_BLOCKS, 4);
        pass2a_key<<<g2, 256, 0, stream>>>(mku, P1, P2, partial);
        pass2b<<<1, 64, 0, stream>>>(partial, P1, P2, (float*)d_out);
    }
}

// Round 10
// 58.902 us; speedup vs baseline: 2.4759x; 2.4759x over previous
//
#include <hip/hip_runtime.h>
#include <math.h>

// Chamfer distance, N=2, D=3 fp32 — tuned brute force (grid experiments r4-r9
// all lost to ~85us of fixed pipeline overhead; r2 brute = 58.8us total).
// r2 re-analysis: pass1 was VALU-ISSUE-bound at 93% (129K cyc/SIMD issue vs
// 119K wall); r3's QPT=8 failed only because its grid was 3 blocks/CU (issue
// efficiency collapsed to 49%). Fix: QPT=8 (halves per-pair issue cost:
// 8 queries served per ds_read_b128, 3.5 VALU/pair) AND SEG=192 so grid =
// 6x63x4 = 1512 blocks = 5.9/CU (r2's occupancy regime).
// VALU floor: 1512*4 waves * 96 iters * 56 instr = 32.5M wave-instr
// -> 63.5K cyc/SIMD = 26.5us. Predict pass1 ~29-34us.
// Determinism: atomicMin on flip-keys is order-independent; fixed-order
// reductions; mk re-initialized by memset each call.

#define BLOCK 256
#define QPT 8            // queries per thread: 8 served per LDS broadcast read
#define SEG 192          // targets per segment -> grid 6x63x4 = 1512 = 5.9/CU
#define P2A_BLOCKS 6
#define P2A_PAD 8

// Order-preserving float->uint key: uint compare == float compare.
__device__ __forceinline__ unsigned fkey(float f) {
    unsigned u = __float_as_uint(f);
    unsigned mask = (unsigned)((int)u >> 31) | 0x80000000u;
    return u ^ mask;
}
__device__ __forceinline__ float fdec(unsigned k) {
    unsigned mask = (k & 0x80000000u) ? 0x80000000u : 0xFFFFFFFFu;
    return __uint_as_float(k ^ mask);
}

__global__ __launch_bounds__(BLOCK) void chamfer_pass1(
    const float* __restrict__ c1, const float* __restrict__ c2,
    int P1, int P2, unsigned* __restrict__ mk_all) {
    const int z = blockIdx.z;            // n*2 + dir
    const int n = z >> 1, dir = z & 1;
    const int Pq = dir ? P2 : P1;
    const int Pt = dir ? P1 : P2;
    const float* Q = (dir ? c2 : c1) + (size_t)n * Pq * 3;
    const float* T = (dir ? c1 : c2) + (size_t)n * Pt * 3;
    unsigned* mk = mk_all + (size_t)n * (P1 + P2) + (dir ? P1 : 0);

    // Stage target tile as (-2x, -2y, -2z, |b|^2); pad with +INF sentinel.
    __shared__ float4 tile[SEG];
    const int t0 = blockIdx.y * SEG;
    const int nt = Pt - t0;              // valid targets (may be < SEG)
    if (threadIdx.x < SEG) {
        const int j = threadIdx.x;
        float4 v;
        if (j < nt) {
            const float* p = T + (size_t)(t0 + j) * 3;
            float x = p[0], y = p[1], w = p[2];
            v = make_float4(-2.f * x, -2.f * y, -2.f * w,
                            fmaf(x, x, fmaf(y, y, w * w)));
        } else {
            v = make_float4(0.f, 0.f, 0.f, INFINITY);
        }
        tile[j] = v;
    }

    const int qbase = blockIdx.x * (BLOCK * QPT) + threadIdx.x;
    float ax[QPT], ay[QPT], az[QPT], m[QPT];
    #pragma unroll
    for (int k = 0; k < QPT; ++k) {
        const int qi = qbase + k * BLOCK;
        ax[k] = 0.f; ay[k] = 0.f; az[k] = 0.f;
        if (qi < Pq) {
            const float* p = Q + (size_t)qi * 3;
            ax[k] = p[0]; ay[k] = p[1]; az[k] = p[2];
        }
        m[k] = INFINITY;
    }
    __syncthreads();

    #pragma unroll 8
    for (int j = 0; j < SEG; j += 2) {
        const float4 b0 = tile[j];       // uniform addr -> broadcast ds_read_b128
        const float4 b1 = tile[j + 1];
        #pragma unroll
        for (int k = 0; k < QPT; ++k) {
            float d0 = fmaf(ax[k], b0.x, fmaf(ay[k], b0.y, fmaf(az[k], b0.z, b0.w)));
            float d1 = fmaf(ax[k], b1.x, fmaf(ay[k], b1.y, fmaf(az[k], b1.z, b1.w)));
            m[k] = fminf(fminf(m[k], d0), d1);   // fuses to v_min3_f32
        }
    }

    // min_j ||a-b||^2 = ||a||^2 + min_j(||b||^2 - 2 a.b)
    #pragma unroll
    for (int k = 0; k < QPT; ++k) {
        const int qi = qbase + k * BLOCK;
        if (qi < Pq) {
            const float sq = fmaf(ax[k], ax[k], fmaf(ay[k], ay[k], az[k] * az[k]));
            atomicMin(&mk[qi], fkey(sq + m[k]));
        }
    }
}

__global__ __launch_bounds__(256) void pass2a(
    const unsigned* __restrict__ mk_all, int P1, int P2,
    float* __restrict__ partial) {
    const int z = blockIdx.y;            // 0..3
    const int b = blockIdx.x;            // 0..P2A_BLOCKS-1
    const int n = z >> 1, dir = z & 1;
    const int Pq = dir ? P2 : P1;
    const unsigned* mk = mk_all + (size_t)n * (P1 + P2) + (dir ? P1 : 0);
    const int span = (Pq + P2A_BLOCKS - 1) / P2A_BLOCKS;
    const int lo = b * span;
    const int hi = min(lo + span, Pq);
    float s = 0.f;
    for (int q = lo + threadIdx.x; q < hi; q += 256) s += fdec(mk[q]);
    __shared__ float red[256];
    red[threadIdx.x] = s;
    __syncthreads();
    for (int off = 128; off > 0; off >>= 1) {
        if (threadIdx.x < off) red[threadIdx.x] += red[threadIdx.x + off];
        __syncthreads();
    }
    if (threadIdx.x == 0) partial[z * P2A_PAD + b] = red[0];
}

__global__ void pass2b(const float* __restrict__ partial,
                       int P1, int P2, float* __restrict__ out) {
    int n = threadIdx.x;
    if (n < 2) {
        float sA = 0.f, sB = 0.f;
        for (int b = 0; b < P2A_BLOCKS; ++b) {
            sA += partial[(n * 2 + 0) * P2A_PAD + b];
            sB += partial[(n * 2 + 1) * P2A_PAD + b];
        }
        out[n] = sA / (float)P1 + sB / (float)P2;
    }
}

extern "C" void kernel_launch(void* const* d_in, const int* in_sizes, int n_in,
                              void* d_out, int out_size, void* d_ws, size_t ws_size,
                              hipStream_t stream) {
    const float* c1 = (const float*)d_in[0];
    const float* c2 = (const float*)d_in[1];
    const int N = 2;
    const int P1 = in_sizes[0] / (N * 3);
    const int P2 = in_sizes[1] / (N * 3);

    unsigned* mk = (unsigned*)d_ws;
    size_t mk_bytes = (size_t)N * (P1 + P2) * sizeof(unsigned);
    float* partial = (float*)((char*)d_ws + ((mk_bytes + 255) & ~(size_t)255));

    // Re-init min keys every call: 0xFFFFFFFF > any encoded key.
    hipMemsetAsync(d_ws, 0xFF, mk_bytes, stream);

    const int Pmax = P1 > P2 ? P1 : P2;
    dim3 g1((Pmax + BLOCK * QPT - 1) / (BLOCK * QPT),
            (Pmax + SEG - 1) / SEG,
            2 * N);
    chamfer_pass1<<<g1, BLOCK, 0, stream>>>(c1, c2, P1, P2, mk);

    dim3 g2(P2A_BLOCKS, 2 * N);
    pass2a<<<g2, 256, 0, stream>>>(mk, P1, P2, partial);

    pass2b<<<1, 64, 0, stream>>>(partial, P1, P2, (float*)d_out);
}